// Round 6
// baseline (345.603 us; speedup 1.0000x reference)
//
#include <hip/hip_runtime.h>

#define B_ 8
#define CQ_ 256
#define CKV_ 512
#define N_ 4096
#define DQK_ 32

typedef __bf16 bf16;
typedef __bf16 bf16x4 __attribute__((ext_vector_type(4)));
typedef __bf16 bf16x8 __attribute__((ext_vector_type(8)));
typedef float f32x4 __attribute__((ext_vector_type(4)));

// ---------------- weight convert fp32 -> bf16 ----------------
__global__ void k_convert_w(const float* __restrict__ Wq, const float* __restrict__ Wk,
                            const float* __restrict__ Wv,
                            bf16* __restrict__ wq, bf16* __restrict__ wk, bf16* __restrict__ wv) {
    int i = blockIdx.x * 256 + threadIdx.x;
    if (i < 8192) wq[i] = (bf16)Wq[i];
    else if (i < 24576) wk[i - 8192] = (bf16)Wk[i - 8192];
    else if (i < 155648) wv[i - 24576] = (bf16)Wv[i - 24576];
}

// ---------------- bilinear resize 32x32 -> 64x64, transposed to [b][n][u] ----------------
__global__ __launch_bounds__(256) void k_resize(const float* __restrict__ kv, bf16* __restrict__ kvr) {
    const int yo = blockIdx.x;   // output row 0..63
    const int b  = blockIdx.y;
    const int tid = threadIdx.x;
    __shared__ float r0[64][33];
    __shared__ float r1[64][33];
    int ty = yo >> 1;
    int y0, y1; float wy0, wy1;
    if ((yo & 1) == 0) { y0 = ty > 0 ? ty - 1 : 0; y1 = ty; wy0 = 0.25f; wy1 = 0.75f; }
    else               { y0 = ty; y1 = ty < 31 ? ty + 1 : 31; wy0 = 0.75f; wy1 = 0.25f; }
    const int u_loc = tid & 63;
    const int xo_base = tid >> 6;
    for (int uc = 0; uc < CKV_; uc += 64) {
        __syncthreads();
        for (int i = 0; i < 8; ++i) {
            int idx = tid + i * 256;
            int u = idx >> 5, x = idx & 31;
            const float* src = kv + ((size_t)b * CKV_ + uc + u) * 1024 + x;
            r0[u][x] = src[y0 * 32];
            r1[u][x] = src[y1 * 32];
        }
        __syncthreads();
        for (int i = 0; i < 16; ++i) {
            int xo = xo_base + i * 4;
            int tx = xo >> 1;
            int xa, xb; float wxa, wxb;
            if ((xo & 1) == 0) { xa = tx > 0 ? tx - 1 : 0; xb = tx; wxa = 0.25f; wxb = 0.75f; }
            else               { xa = tx; xb = tx < 31 ? tx + 1 : 31; wxa = 0.75f; wxb = 0.25f; }
            float v0 = wxa * r0[u_loc][xa] + wxb * r0[u_loc][xb];
            float v1 = wxa * r1[u_loc][xa] + wxb * r1[u_loc][xb];
            float val = wy0 * v0 + wy1 * v1;
            kvr[((size_t)b * N_ + yo * 64 + xo) * CKV_ + uc + u_loc] = (bf16)val;
        }
    }
}

// ---------------- fused: transpose query tile to LDS + q projection ----------------
// NOTE: output is pre-scaled by log2(e) so the flash kernel can use exp2.
__global__ __launch_bounds__(256) void k_proj_q_fused(const float* __restrict__ query,
                                                      const bf16* __restrict__ W,     // [32][256]
                                                      const float* __restrict__ bias, // [32]
                                                      bf16* __restrict__ qTb) {       // [B][N][32]
    __shared__ bf16 tile[64][264];   // [n][c], row stride 528B (16B-aligned)
    const int n0 = blockIdx.x * 64;
    const int b  = blockIdx.y;
    const int tid = threadIdx.x;
    const int xi = tid & 15, c0 = tid >> 4;
    for (int pass = 0; pass < 16; ++pass) {
        int c = c0 + pass * 16;
        const float4 v = *(const float4*)(query + ((size_t)b * CQ_ + c) * N_ + n0 + xi * 4);
        tile[xi * 4 + 0][c] = (bf16)v.x;
        tile[xi * 4 + 1][c] = (bf16)v.y;
        tile[xi * 4 + 2][c] = (bf16)v.z;
        tile[xi * 4 + 3][c] = (bf16)v.w;
    }
    __syncthreads();
    const int w = tid >> 6, lane = tid & 63;
    const int l16 = lane & 15, quad = lane >> 4;
    const int ct = w & 1, nh = w >> 1;
    f32x4 acc[2];
    acc[0] = (f32x4){0.f, 0.f, 0.f, 0.f}; acc[1] = (f32x4){0.f, 0.f, 0.f, 0.f};
    const bf16* aptr = W + (ct * 16 + l16) * CQ_ + quad * 8;
#pragma unroll
    for (int ks = 0; ks < 8; ++ks) {
        bf16x8 af = *(const bf16x8*)(aptr + ks * 32);
        for (int j = 0; j < 2; ++j) {
            bf16x8 bfv = *(const bf16x8*)&tile[nh * 32 + j * 16 + l16][ks * 32 + quad * 8];
            acc[j] = __builtin_amdgcn_mfma_f32_16x16x32_bf16(af, bfv, acc[j], 0, 0, 0);
        }
    }
    const float LOG2E = 1.4426950408889634f;
    for (int j = 0; j < 2; ++j)
        for (int r = 0; r < 4; ++r) {
            int d = ct * 16 + quad * 4 + r;
            int n = n0 + nh * 32 + j * 16 + l16;
            qTb[((size_t)b * N_ + n) * DQK_ + d] = (bf16)((acc[j][r] + bias[d]) * LOG2E);
        }
}

// ---------------- k projection ----------------
__global__ __launch_bounds__(256) void k_proj_k(const bf16* __restrict__ W,     // [32][512]
                                                const float* __restrict__ bias, // [32]
                                                const bf16* __restrict__ Bm,    // [B][N][512]
                                                bf16* __restrict__ outT) {      // [B][N][32]
    const int mb = blockIdx.x * 128;
    const int b  = blockIdx.y;
    const int tid = threadIdx.x;
    const int w = tid >> 6, lane = tid & 63;
    const int l16 = lane & 15, quad = lane >> 4;
    const int ct = w & 1;
    const int mhalf = (w >> 1) * 64;
    f32x4 acc[4];
    for (int j = 0; j < 4; ++j) acc[j] = (f32x4){0.f, 0.f, 0.f, 0.f};
    const bf16* aptr  = W + (ct * 16 + l16) * CKV_ + quad * 8;
    const bf16* bbase = Bm + ((size_t)b * N_ + mb + mhalf) * CKV_ + quad * 8;
#pragma unroll
    for (int ks = 0; ks < 16; ++ks) {
        bf16x8 af = *(const bf16x8*)(aptr + ks * 32);
        for (int j = 0; j < 4; ++j) {
            bf16x8 bfv = *(const bf16x8*)(bbase + (size_t)(j * 16 + l16) * CKV_ + ks * 32);
            acc[j] = __builtin_amdgcn_mfma_f32_16x16x32_bf16(af, bfv, acc[j], 0, 0, 0);
        }
    }
    for (int j = 0; j < 4; ++j)
        for (int r = 0; r < 4; ++r) {
            int d = ct * 16 + quad * 4 + r;
            int m = mb + mhalf + j * 16 + l16;
            outT[((size_t)b * N_ + m) * DQK_ + d] = (bf16)(acc[j][r] + bias[d]);
        }
}

// ---------------- v projection ----------------
__global__ __launch_bounds__(256) void k_proj_v(const bf16* __restrict__ W,     // [256][512]
                                                const float* __restrict__ bias, // [256]
                                                const bf16* __restrict__ Bm,    // [B][N][512]
                                                bf16* __restrict__ vout) {      // [B][256][N]
    const int mb = blockIdx.x * 64;
    const int b  = blockIdx.y;
    const int tid = threadIdx.x;
    const int w = tid >> 6, lane = tid & 63;
    const int l16 = lane & 15, quad = lane >> 4;
    f32x4 acc[4][4];
    for (int i = 0; i < 4; ++i) for (int j = 0; j < 4; ++j) acc[i][j] = (f32x4){0.f, 0.f, 0.f, 0.f};
    const bf16* bbase = Bm + ((size_t)b * N_ + mb) * CKV_ + quad * 8;
#pragma unroll 4
    for (int ks = 0; ks < 16; ++ks) {
        bf16x8 bfv[4];
        for (int j = 0; j < 4; ++j)
            bfv[j] = *(const bf16x8*)(bbase + (size_t)(j * 16 + l16) * CKV_ + ks * 32);
        for (int i = 0; i < 4; ++i) {
            bf16x8 af = *(const bf16x8*)(W + (size_t)((w * 4 + i) * 16 + l16) * CKV_ + ks * 32 + quad * 8);
            for (int j = 0; j < 4; ++j)
                acc[i][j] = __builtin_amdgcn_mfma_f32_16x16x32_bf16(af, bfv[j], acc[i][j], 0, 0, 0);
        }
    }
    for (int i = 0; i < 4; ++i)
        for (int r = 0; r < 4; ++r) {
            int c = (w * 4 + i) * 16 + quad * 4 + r;
            float bvs = bias[c];
            for (int j = 0; j < 4; ++j) {
                int m = mb + j * 16 + l16;
                vout[((size_t)b * CQ_ + c) * N_ + m] = (bf16)(acc[i][j][r] + bvs);
            }
        }
}

// ---------------- flash attention: barrier-free + pipelined single-buffer P ----------------
// Per-wave in-order DS: reads of P(mt-1) are issued BEFORE the aliasing writes
// of P(mt) each iteration -> single buffer behaves like a double buffer, and
// the LDS round-trip latency hides behind the whole S-phase. exp2 (q
// pre-scaled by log2e) removes 64 v_mul/iter; softmax denominator comes from
// an all-ones MFMA A-operand (accl), removing 64 v_add/iter + end shuffles.
// Grid (8,64): x=batch -> all blocks sharing K/V land on one XCD's L2.
__global__ __launch_bounds__(256, 2) void k_flash(const bf16* __restrict__ qT,   // [B][N][32] (pre-scaled)
                                                  const bf16* __restrict__ kT,   // [B][N][32]
                                                  const bf16* __restrict__ vv,   // [B][256][N]
                                                  const float* __restrict__ query,
                                                  const float* __restrict__ gamma,
                                                  float* __restrict__ out) {
    __shared__ bf16 P[4][64][72];   // [wave][n][m-phys]; single buffer
    const int b  = blockIdx.x;
    const int n0 = blockIdx.y * 64;
    const int tid = threadIdx.x;
    const int w = tid >> 6, lane = tid & 63;
    const int l16 = lane & 15, quad = lane >> 4;
    const int swz = (l16 & 3) ^ ((l16 >> 3) << 1);   // bank-spreading chunk XOR

    // Q fragments (B-operand), loop-invariant
    bf16x8 qfrag[4];
    for (int jn = 0; jn < 4; ++jn)
        qfrag[jn] = *(const bf16x8*)(qT + ((size_t)b * N_ + n0 + jn * 16 + l16) * DQK_ + quad * 8);

    const bf16 one = (bf16)1.0f;
    const bf16x8 ones = {one, one, one, one, one, one, one, one};
    const f32x4 zed = {0.f, 0.f, 0.f, 0.f};

    f32x4 acc[4][4];   // c = w*64+i*16+quad*4+r, n = n0+j*16+l16
    for (int i = 0; i < 4; ++i) for (int j = 0; j < 4; ++j) acc[i][j] = zed;
    f32x4 accl[4];     // softmax denominators (all 4 components equal)
    for (int j = 0; j < 4; ++j) accl[j] = zed;

    // lane pointers, advanced per iter; im/ks handled by small imm offsets
    const bf16* kp = kT + ((size_t)b * N_ + l16) * DQK_ + quad * 8;
    const bf16* vp[4];
    for (int i = 0; i < 4; ++i)
        vp[i] = vv + ((size_t)b * CQ_ + w * 64 + i * 16 + l16) * N_ + quad * 8;

    bf16 (* __restrict__ Pw)[72] = P[w];

    bf16x8 kf[4], vf[2][4], pf[2][4];
    // preload K(0)
    for (int im = 0; im < 4; ++im) kf[im] = *(const bf16x8*)(kp + im * 16 * DQK_);
    kp += 64 * DQK_;

    for (int mt = 0; mt < 64; ++mt) {
        // (1) issue reads of P(mt-1) BEFORE this iter's writes (in-order DS)
        if (mt)
            for (int ks = 0; ks < 2; ++ks)
                for (int j = 0; j < 4; ++j)
                    pf[ks][j] = *(const bf16x8*)&Pw[j * 16 + l16]
                                    [((((ks << 1) | (quad >> 1)) ^ swz) << 4) + ((quad & 1) << 3)];
        // (2) S(mt) = K Q^T (redundant per wave), exp2 in regs, write P(mt)
        for (int jn = 0; jn < 4; ++jn)
            for (int im = 0; im < 4; ++im) {
                f32x4 s = __builtin_amdgcn_mfma_f32_16x16x32_bf16(kf[im], qfrag[jn], zed, 0, 0, 0);
                bf16x4 pk;
                for (int r = 0; r < 4; ++r) pk[r] = (bf16)__builtin_amdgcn_exp2f(s[r]);
                *(bf16x4*)&Pw[jn * 16 + l16][((im ^ swz) << 4) + quad * 4] = pk;
            }
        // (3) prefetch K(mt+1)  (last iter overreads 4KB into ws scratch - harmless)
        for (int im = 0; im < 4; ++im) kf[im] = *(const bf16x8*)(kp + im * 16 * DQK_);
        kp += 64 * DQK_;
        // (4) PV(mt-1): O += V P^T, denominators via ones-row MFMA
        if (mt)
            for (int ks = 0; ks < 2; ++ks)
                for (int j = 0; j < 4; ++j) {
                    accl[j] = __builtin_amdgcn_mfma_f32_16x16x32_bf16(ones, pf[ks][j], accl[j], 0, 0, 0);
                    for (int i = 0; i < 4; ++i)
                        acc[i][j] = __builtin_amdgcn_mfma_f32_16x16x32_bf16(vf[ks][i], pf[ks][j], acc[i][j], 0, 0, 0);
                }
        // (5) load V(mt) for next iter's PV
        for (int ks = 0; ks < 2; ++ks)
            for (int i = 0; i < 4; ++i)
                vf[ks][i] = *(const bf16x8*)(vp[i] + ks * 32);
        for (int i = 0; i < 4; ++i) vp[i] += 64;
    }
    // epilogue: PV(63)
    for (int ks = 0; ks < 2; ++ks)
        for (int j = 0; j < 4; ++j)
            pf[ks][j] = *(const bf16x8*)&Pw[j * 16 + l16]
                            [((((ks << 1) | (quad >> 1)) ^ swz) << 4) + ((quad & 1) << 3)];
    for (int ks = 0; ks < 2; ++ks)
        for (int j = 0; j < 4; ++j) {
            accl[j] = __builtin_amdgcn_mfma_f32_16x16x32_bf16(ones, pf[ks][j], accl[j], 0, 0, 0);
            for (int i = 0; i < 4; ++i)
                acc[i][j] = __builtin_amdgcn_mfma_f32_16x16x32_bf16(vf[ks][i], pf[ks][j], acc[i][j], 0, 0, 0);
        }

    float linv[4];
    for (int j = 0; j < 4; ++j) linv[j] = 1.f / accl[j][0];
    const float g = gamma[0];
    for (int i = 0; i < 4; ++i)
        for (int r = 0; r < 4; ++r) {
            int c = w * 64 + i * 16 + quad * 4 + r;
            for (int j = 0; j < 4; ++j) {
                int n = n0 + j * 16 + l16;
                size_t idx = ((size_t)b * CQ_ + c) * N_ + n;
                out[idx] = g * acc[i][j][r] * linv[j] + query[idx];
            }
        }
}

extern "C" void kernel_launch(void* const* d_in, const int* in_sizes, int n_in,
                              void* d_out, int out_size, void* d_ws, size_t ws_size,
                              hipStream_t stream) {
    const float* query     = (const float*)d_in[0];
    const float* key_value = (const float*)d_in[1];
    const float* Wq = (const float*)d_in[2];
    const float* bq = (const float*)d_in[3];
    const float* Wk = (const float*)d_in[4];
    const float* bk = (const float*)d_in[5];
    const float* Wv = (const float*)d_in[6];
    const float* bv = (const float*)d_in[7];
    const float* gamma = (const float*)d_in[8];
    float* out = (float*)d_out;

    char* ws = (char*)d_ws;
    bf16* kvr  = (bf16*)(ws);              // [8][4096][512]  33,554,432 B
    bf16* vbuf = (bf16*)(ws + 33554432);   // [8][256][4096]  16,777,216 B
    bf16* qTb  = (bf16*)(ws + 50331648);   // [8][4096][32]    2,097,152 B
    bf16* kTb  = (bf16*)(ws + 52428800);   // [8][4096][32]    2,097,152 B
    bf16* wqb  = (bf16*)(ws + 54525952);   // [32][256]           16,384 B
    bf16* wkb  = (bf16*)(ws + 54542336);   // [32][512]           32,768 B
    bf16* wvb  = (bf16*)(ws + 54575104);   // [256][512]         262,144 B

    k_convert_w<<<608, 256, 0, stream>>>(Wq, Wk, Wv, wqb, wkb, wvb);
    k_resize<<<dim3(64, 8), 256, 0, stream>>>(key_value, kvr);
    k_proj_q_fused<<<dim3(64, 8), 256, 0, stream>>>(query, wqb, bq, qTb);
    k_proj_k<<<dim3(32, 8), 256, 0, stream>>>(wkb, bk, kvr, kTb);
    k_proj_v<<<dim3(64, 8), 256, 0, stream>>>(wvb, bv, kvr, vbuf);
    k_flash<<<dim3(8, 64), 256, 0, stream>>>(qTb, kTb, vbuf, query, gamma, out);
}